// Round 11
// baseline (203.141 us; speedup 1.0000x reference)
//
#include <hip/hip_runtime.h>
#include <math.h>

#define NN 16384
#define DD 64
#define HH 128
#define TT 20

typedef _Float16 f16;
typedef f16 f16x8 __attribute__((ext_vector_type(8)));
typedef f16 f16x2v __attribute__((ext_vector_type(2)));
typedef __fp16 h16x2 __attribute__((ext_vector_type(2)));   // cvt_pkrtz result type
typedef float f32x4 __attribute__((ext_vector_type(4)));

#define LOG2E2 2.8853900817779268   // 2*log2(e): tanh(x) = 1 - 2/(exp2(LOG2E2*x)+1)

// sigma2 frag bijection (identical for A and B frags of every GEMM -> correct for
// any internal HW k enumeration): element (lane, j) of a frag-tile holds
//   M[k = 32*kt + 16*(j>>2) + 4*(lane>>4) + (j&3)][m/n = 16*t + (lane&15)].
// KEY PROPERTY (full-m wave): C value (m-tile mt, reg) at lane (g,r) is exactly
// B-frag element j = 4*(mt&1)+reg of k-tile kt = mt>>1 at the SAME lane.
// One wave computing ALL m-tiles chains GEMM->act->GEMM entirely in registers:
// no LDS, no barriers, no cross-lane traffic.
#define W1F 0        // [mt 8][kt 2][64][8]  A1[m=h1col][k=d]   = W1^T*LOG2E2 (16 KB)
#define W2F 8192     // [mt 8][kt 4][64][8]  A2[m=h2col][k=h1]  = W2^T*LOG2E2 (32 KB)
#define W3F 24576    // [mt 4][kt 4][64][8]  A3[m=d][k=h2col]   = W3^T        (16 KB)

#define PIN(x) asm volatile("" : "+v"(x))

__device__ __forceinline__ float texp(float c) {   // tanh from pre-scaled preact
    float t = __builtin_amdgcn_exp2f(c);
    return fmaf(-2.0f, __builtin_amdgcn_rcpf(t + 1.0f), 1.0f);
}
__device__ __forceinline__ f16x2v pk2(float a, float b) {
    return __builtin_bit_cast(f16x2v, __builtin_amdgcn_cvt_pkrtz(a, b));
}
#define CC(x) ((f16)(float)(x))
// unpack packed-k element (m-tile mt, reg)
#define KE(KP, MT, RG) ((float)((RG) & 1 ? (KP)[2*(MT) + ((RG) >> 1)].y \
                                         : (KP)[2*(MT) + ((RG) >> 1)].x))

// Weight prep: fp32 [k][m] row-major -> f16 sigma2 frag-major A-tiles (W1,W2 scaled).
__global__ void __launch_bounds__(256) prep_w(
    const float* __restrict__ W1, const float* __restrict__ W2,
    const float* __restrict__ W3, f16* __restrict__ wf)
{
    int t = blockIdx.x * 256 + threadIdx.x;          // 0..32767
    int l = (t >> 3) & 63, j = t & 7, g = l >> 4, r = l & 15;
    int kj = 16 * (j >> 2) + 4 * g + (j & 3);        // sigma2 within-tile k
    float v;
    if (t < 8192)       { int kt = (t >> 9) & 1, mt = t >> 10;
        v = W1[(32*kt + kj) * HH + 16*mt + r] * (float)LOG2E2; }
    else if (t < 24576) { int u = t - 8192;  int kt = (u >> 9) & 3, mt = u >> 11;
        v = W2[(32*kt + kj) * HH + 16*mt + r] * (float)LOG2E2; }
    else                { int u = t - 24576; int kt = (u >> 9) & 3, mt = u >> 11;
        v = W3[(32*kt + kj) * DD + 16*mt + r]; }
    wf[t] = (f16)v;
}

// One wave (64 threads) per 16-row n-tile. 1024 blocks = 4 waves/CU, 1 wave/SIMD.
// All weights live in the unified VGPR/AGPR file (64 f16x8 = 256 regs -> AGPR);
// activations chain register-to-register via the sigma2 property. No LDS.
__global__ void __launch_bounds__(64, 1) ode_mfma(
    const float* __restrict__ tg, const f16* __restrict__ wf,
    const float* __restrict__ b1, const float* __restrict__ b2,
    const float* __restrict__ b3,
    const float* __restrict__ x0, float* __restrict__ out)
{
    const int lane = threadIdx.x;
    const int g    = lane >> 4;           // 0..3
    const int r    = lane & 15;
    const int row  = (blockIdx.x << 4) + r;

    // ---- ALL weight fragments -> registers (256 regs, expect AGPR) ----
    f16x8 A1r[8][2], A2r[8][4], A3r[4][4];
    #pragma unroll
    for (int mt = 0; mt < 8; ++mt)
        #pragma unroll
        for (int kt = 0; kt < 2; ++kt) {
            A1r[mt][kt] = *(const f16x8*)(wf + W1F + ((mt*2 + kt)*64 + lane)*8);
            PIN(A1r[mt][kt]);
        }
    #pragma unroll
    for (int mt = 0; mt < 8; ++mt)
        #pragma unroll
        for (int kt = 0; kt < 4; ++kt) {
            A2r[mt][kt] = *(const f16x8*)(wf + W2F + ((mt*4 + kt)*64 + lane)*8);
            PIN(A2r[mt][kt]);
        }
    #pragma unroll
    for (int mt = 0; mt < 4; ++mt)
        #pragma unroll
        for (int kt = 0; kt < 4; ++kt) {
            A3r[mt][kt] = *(const f16x8*)(wf + W3F + ((mt*4 + kt)*64 + lane)*8);
            PIN(A3r[mt][kt]);
        }

    // biases packed f16 (40 VGPR); b1/b2 pre-scaled by LOG2E2
    f16x2v b1p[16], b2p[16], b3p[8];
    #pragma unroll
    for (int mt = 0; mt < 8; ++mt)
        #pragma unroll
        for (int q = 0; q < 2; ++q) {
            int o = 16*mt + 4*g + 2*q;
            b1p[2*mt+q] = pk2(b1[o] * (float)LOG2E2, b1[o+1] * (float)LOG2E2);
            b2p[2*mt+q] = pk2(b2[o] * (float)LOG2E2, b2[o+1] * (float)LOG2E2);
        }
    #pragma unroll
    for (int mt = 0; mt < 4; ++mt)
        #pragma unroll
        for (int q = 0; q < 2; ++q) {
            int o = 16*mt + 4*g + 2*q;
            b3p[2*mt+q] = pk2(b3[o], b3[o+1]);
        }

    // ---- state: y fp32 [d-tile][reg], packed y, packed stage-input ys ----
    float  yr[4][4];
    f16x2v yrp[8], ysp[8];
    #pragma unroll
    for (int mt = 0; mt < 4; ++mt) {
        float4 v = *(const float4*)&x0[row * DD + 16*mt + 4*g];
        yr[mt][0] = v.x; yr[mt][1] = v.y; yr[mt][2] = v.z; yr[mt][3] = v.w;
        *(float4*)&out[row * (TT * DD) + 16*mt + 4*g] = v;
        yrp[2*mt]   = pk2(v.x, v.y);
        yrp[2*mt+1] = pk2(v.z, v.w);
        ysp[2*mt] = yrp[2*mt]; ysp[2*mt+1] = yrp[2*mt+1];
    }

    f16x2v k1p[8], k2p[8], k3p[8], k4p[8], k5p[8], k6p[8];

    union BU { f16x8 v8; f16x2v p[4]; h16x2 h[4]; };

    // One MLP eval: ysp (packed B1) -> dstp[8] = packed k. Pure registers.
    auto EVAL = [&](f16x2v* dstp) {
        f32x4 c[8];
        #pragma unroll
        for (int mt = 0; mt < 8; ++mt)
            #pragma unroll
            for (int rg = 0; rg < 4; ++rg) c[mt][rg] = KE(b1p, mt, rg);
        #pragma unroll
        for (int kt = 0; kt < 2; ++kt) {
            BU u;
            #pragma unroll
            for (int q = 0; q < 4; ++q) u.p[q] = ysp[4*kt + q];
            #pragma unroll
            for (int mt = 0; mt < 8; ++mt)
                c[mt] = __builtin_amdgcn_mfma_f32_16x16x32_f16(A1r[mt][kt], u.v8, c[mt], 0, 0, 0);
        }
        f32x4 d[8];
        #pragma unroll
        for (int mt = 0; mt < 8; ++mt)
            #pragma unroll
            for (int rg = 0; rg < 4; ++rg) d[mt][rg] = KE(b2p, mt, rg);
        #pragma unroll
        for (int kt = 0; kt < 4; ++kt) {       // h1 = texp(C) packed on the fly
            BU u;
            u.h[0] = __builtin_amdgcn_cvt_pkrtz(texp(c[2*kt][0]),   texp(c[2*kt][1]));
            u.h[1] = __builtin_amdgcn_cvt_pkrtz(texp(c[2*kt][2]),   texp(c[2*kt][3]));
            u.h[2] = __builtin_amdgcn_cvt_pkrtz(texp(c[2*kt+1][0]), texp(c[2*kt+1][1]));
            u.h[3] = __builtin_amdgcn_cvt_pkrtz(texp(c[2*kt+1][2]), texp(c[2*kt+1][3]));
            #pragma unroll
            for (int mt = 0; mt < 8; ++mt)
                d[mt] = __builtin_amdgcn_mfma_f32_16x16x32_f16(A2r[mt][kt], u.v8, d[mt], 0, 0, 0);
        }
        f32x4 e[4];
        #pragma unroll
        for (int mt = 0; mt < 4; ++mt)
            #pragma unroll
            for (int rg = 0; rg < 4; ++rg) e[mt][rg] = KE(b3p, mt, rg);
        #pragma unroll
        for (int kt = 0; kt < 4; ++kt) {       // h2 = texp(D) packed on the fly
            BU u;
            u.h[0] = __builtin_amdgcn_cvt_pkrtz(texp(d[2*kt][0]),   texp(d[2*kt][1]));
            u.h[1] = __builtin_amdgcn_cvt_pkrtz(texp(d[2*kt][2]),   texp(d[2*kt][3]));
            u.h[2] = __builtin_amdgcn_cvt_pkrtz(texp(d[2*kt+1][0]), texp(d[2*kt+1][1]));
            u.h[3] = __builtin_amdgcn_cvt_pkrtz(texp(d[2*kt+1][2]), texp(d[2*kt+1][3]));
            #pragma unroll
            for (int mt = 0; mt < 4; ++mt)
                e[mt] = __builtin_amdgcn_mfma_f32_16x16x32_f16(A3r[mt][kt], u.v8, e[mt], 0, 0, 0);
        }
        #pragma unroll
        for (int mt = 0; mt < 4; ++mt) {
            dstp[2*mt]   = pk2(e[mt][0], e[mt][1]);
            dstp[2*mt+1] = pk2(e[mt][2], e[mt][3]);
        }
    };

    EVAL(k1p);   // k1 = f(x0)

// stage combo in packed f16 (v_pk_fma): ysp = yrp + dt*(sum C_j k_j)
#define COMBOP(C1, C2, C3, C4, C5, C6) do {                                  \
    const f16x2v _c1 = {CC(C1), CC(C1)}, _c2 = {CC(C2), CC(C2)},             \
                 _c3 = {CC(C3), CC(C3)}, _c4 = {CC(C4), CC(C4)},             \
                 _c5 = {CC(C5), CC(C5)}, _c6 = {CC(C6), CC(C6)};             \
    _Pragma("unroll")                                                        \
    for (int p = 0; p < 8; ++p) {                                            \
        f16x2v a = _c1 * k1p[p];                                             \
        if ((C2) != 0.0) a = _c2 * k2p[p] + a;                               \
        if ((C3) != 0.0) a = _c3 * k3p[p] + a;                               \
        if ((C4) != 0.0) a = _c4 * k4p[p] + a;                               \
        if ((C5) != 0.0) a = _c5 * k5p[p] + a;                               \
        if ((C6) != 0.0) a = _c6 * k6p[p] + a;                               \
        ysp[p] = dt2 * a + yrp[p];                                           \
    } } while (0)

    #pragma unroll 1
    for (int s = 0; s < TT - 1; ++s) {
        const float dtc = tg[s + 1] - tg[s];
        const f16x2v dt2 = {(f16)dtc, (f16)dtc};

        COMBOP(1.0/5.0, 0, 0, 0, 0, 0);                                     EVAL(k2p);
        COMBOP(3.0/40.0, 9.0/40.0, 0, 0, 0, 0);                             EVAL(k3p);
        COMBOP(44.0/45.0, -56.0/15.0, 32.0/9.0, 0, 0, 0);                   EVAL(k4p);
        COMBOP(19372.0/6561.0, -25360.0/2187.0, 64448.0/6561.0,
               -212.0/729.0, 0, 0);                                         EVAL(k5p);
        COMBOP(9017.0/3168.0, -355.0/33.0, 46732.0/5247.0, 49.0/176.0,
               -5103.0/18656.0, 0);                                         EVAL(k6p);

        // ---- y5 in fp32 (accumulates across steps) ----
        #pragma unroll
        for (int mt = 0; mt < 4; ++mt) {
            float y5[4];
            #pragma unroll
            for (int rg = 0; rg < 4; ++rg) {
                float a = (float)(35.0/384.0) * KE(k1p, mt, rg);
                a = fmaf((float)(500.0/1113.0),   KE(k3p, mt, rg), a);
                a = fmaf((float)(125.0/192.0),    KE(k4p, mt, rg), a);
                a = fmaf((float)(-2187.0/6784.0), KE(k5p, mt, rg), a);
                a = fmaf((float)(11.0/84.0),      KE(k6p, mt, rg), a);
                y5[rg] = fmaf(dtc, a, yr[mt][rg]);
                yr[mt][rg] = y5[rg];
            }
            *(float4*)&out[row * (TT * DD) + (s + 1) * DD + 16*mt + 4*g] =
                make_float4(y5[0], y5[1], y5[2], y5[3]);
            yrp[2*mt]   = pk2(y5[0], y5[1]);
            yrp[2*mt+1] = pk2(y5[2], y5[3]);
        }
        if (s < TT - 2) {                      // FSAL: k7 -> next k1 (skip last step)
            #pragma unroll
            for (int p = 0; p < 8; ++p) ysp[p] = yrp[p];
            EVAL(k1p);
        }
    }
#undef COMBOP
}

extern "C" void kernel_launch(void* const* d_in, const int* in_sizes, int n_in,
                              void* d_out, int out_size, void* d_ws, size_t ws_size,
                              hipStream_t stream) {
    (void)in_sizes; (void)n_in; (void)out_size; (void)ws_size;
    const float* tg = (const float*)d_in[0];
    const float* x0 = (const float*)d_in[1];
    const float* W1 = (const float*)d_in[2];
    const float* b1 = (const float*)d_in[3];
    const float* W2 = (const float*)d_in[4];
    const float* b2 = (const float*)d_in[5];
    const float* W3 = (const float*)d_in[6];
    const float* b3 = (const float*)d_in[7];
    float* out = (float*)d_out;
    f16*   wf  = (f16*)d_ws;   // 64 KB sigma2 frag-major f16 weights (W1,W2 pre-scaled)

    hipLaunchKernelGGL(prep_w, dim3(128), dim3(256), 0, stream, W1, W2, W3, wf);
    hipLaunchKernelGGL(ode_mfma, dim3(1024), dim3(64), 0, stream,
                       tg, wf, b1, b2, b3, x0, out);
}

// Round 12
// 181.871 us; speedup vs baseline: 1.1170x; 1.1170x over previous
//
#include <hip/hip_runtime.h>
#include <math.h>

#define NN 16384
#define DD 64
#define HH 128
#define TT 20

typedef _Float16 f16;
typedef f16 f16x8 __attribute__((ext_vector_type(8)));
typedef f16 f16x2v __attribute__((ext_vector_type(2)));
typedef __fp16 h16x2 __attribute__((ext_vector_type(2)));   // cvt_pkrtz result type
typedef __fp16 h16x4 __attribute__((ext_vector_type(4)));
typedef float f32x4 __attribute__((ext_vector_type(4)));

#define LOG2E2 2.8853900817779268   // 2*log2(e): tanh(x) = 1 - 2/(exp2(LOG2E2*x)+1)

// sigma2 frag bijection (identical for A and B frags of every GEMM -> correct for
// any internal HW k enumeration): element (lane, j) of a frag-tile holds
//   M[k = 32*kt + 16*(j>>2) + 4*(lane>>4) + (j&3)][m/n = 16*t + (lane&15)].
// Wave owning m-tiles {2mp,2mp+1} ends a GEMM with lane (g,r) holding C values
// at exactly j=0..7 of the next GEMM's B-frag at the same lane -> C->B repack is
// one lane-contiguous ds_write_b128, no cross-lane traffic.
// Global wf layout (f16 units): W1/W2 PRE-SCALED by LOG2E2 (tanh fusion).
#define W1F 0        // [mt 8][kt 2][64][8]  A1[m=h1col][k=d]   = W1^T*LOG2E2 (16 KB)
#define W2F 8192     // [mt 8][kt 4][64][8]  A2[m=h2col][k=h1]  = W2^T*LOG2E2 (32 KB)
#define W3F 24576    // [mt 4][kt 4][64][8]  A3[m=d][k=h2col]   = W3^T        (16 KB)
// LDS (activations only, one n-tile per block, 10 KB):
#define YST 0        // [kt 2][64][8]  B1[k=d][n=row]      (2 KB)
#define H1T 1024     // [kt 4][64][8]  B2[k=h1col][n=row]  (4 KB)
#define H2T 3072     // [kt 4][64][8]  B3[k=h2col][n=row]  (4 KB)
#define SMTOT 5120

#define PIN(x) asm volatile("" : "+v"(x))

__device__ __forceinline__ float texp(float c) {   // tanh from pre-scaled preact
    float t = __builtin_amdgcn_exp2f(c);
    return fmaf(-2.0f, __builtin_amdgcn_rcpf(t + 1.0f), 1.0f);
}
__device__ __forceinline__ f16x2v pk2(float a, float b) {
    return __builtin_bit_cast(f16x2v, __builtin_amdgcn_cvt_pkrtz(a, b));
}
#define CC(x) ((f16)(float)(x))
#define KF(KP, K) ((float)((K) & 1 ? (KP)[(K) >> 1].y : (KP)[(K) >> 1].x))

// Weight prep: fp32 [k][m] row-major -> f16 sigma2 frag-major A-tiles (W1,W2 scaled).
__global__ void __launch_bounds__(256) prep_w(
    const float* __restrict__ W1, const float* __restrict__ W2,
    const float* __restrict__ W3, f16* __restrict__ wf)
{
    int t = blockIdx.x * 256 + threadIdx.x;          // 0..32767
    int l = (t >> 3) & 63, j = t & 7, g = l >> 4, r = l & 15;
    int kj = 16 * (j >> 2) + 4 * g + (j & 3);        // sigma2 within-tile k
    float v;
    if (t < 8192)       { int kt = (t >> 9) & 1, mt = t >> 10;
        v = W1[(32*kt + kj) * HH + 16*mt + r] * (float)LOG2E2; }
    else if (t < 24576) { int u = t - 8192;  int kt = (u >> 9) & 3, mt = u >> 11;
        v = W2[(32*kt + kj) * HH + 16*mt + r] * (float)LOG2E2; }
    else                { int u = t - 24576; int kt = (u >> 9) & 3, mt = u >> 11;
        v = W3[(32*kt + kj) * DD + 16*mt + r]; }
    wf[t] = (f16)v;
}

// Block = 4 waves = one n-tile (16 rows); 1024 blocks = 4 blocks/CU, 4 waves/SIMD.
// Macro-stepping: 9 double-interval DOPRI5 steps (odd grid points via the standard
// order-4 dense-output interpolant from k1,k3..k7) + 1 single final step.
// 60 MLP evals total vs 115 for per-interval stepping.
__global__ void __launch_bounds__(256, 4) ode_mfma(
    const float* __restrict__ tg, const f16* __restrict__ wf,
    const float* __restrict__ b1, const float* __restrict__ b2,
    const float* __restrict__ b3,
    const float* __restrict__ x0, float* __restrict__ out)
{
    __shared__ __align__(16) f16 sm[SMTOT];

    const int tid  = threadIdx.x;
    const int lane = tid & 63;
    const int mp   = tid >> 6;            // 0..3: m-pair (G1/G2 m-tiles 2mp,2mp+1); G3 m-tile
    const int g    = lane >> 4;           // 0..3
    const int r    = lane & 15;
    const int row  = (blockIdx.x << 4) + r;

    // ---- weight fragments (sigma2-packed) -> registers ----
    f16x8 A1r[2][2], A2r[2][4], A3r[4];
    #pragma unroll
    for (int mi = 0; mi < 2; ++mi)
        #pragma unroll
        for (int kt = 0; kt < 2; ++kt) {
            A1r[mi][kt] = *(const f16x8*)(wf + W1F + (((2*mp+mi)*2 + kt)*64 + lane)*8);
            PIN(A1r[mi][kt]);
        }
    #pragma unroll
    for (int mi = 0; mi < 2; ++mi)
        #pragma unroll
        for (int kt = 0; kt < 4; ++kt) {
            A2r[mi][kt] = *(const f16x8*)(wf + W2F + (((2*mp+mi)*4 + kt)*64 + lane)*8);
            PIN(A2r[mi][kt]);
        }
    #pragma unroll
    for (int kt = 0; kt < 4; ++kt) {
        A3r[kt] = *(const f16x8*)(wf + W3F + ((mp*4 + kt)*64 + lane)*8);
        PIN(A3r[kt]);
    }

    // biases packed f16; b1/b2 pre-scaled
    f16x2v b1p[2][2], b2p[2][2], b3p[2];
    #pragma unroll
    for (int mi = 0; mi < 2; ++mi)
        #pragma unroll
        for (int q = 0; q < 2; ++q) {
            int o = 32*mp + 16*mi + 4*g + 2*q;
            b1p[mi][q] = pk2(b1[o] * (float)LOG2E2, b1[o+1] * (float)LOG2E2);
            b2p[mi][q] = pk2(b2[o] * (float)LOG2E2, b2[o+1] * (float)LOG2E2);
        }
    #pragma unroll
    for (int q = 0; q < 2; ++q)
        b3p[q] = pk2(b3[16*mp + 4*g + 2*q], b3[16*mp + 4*g + 2*q + 1]);

    // lane-contiguous frag slots (f16 units)
    const int hDst  = (mp * 64 + lane) * 8;                          // b128 dest (tile kt=mp)
    const int ysIdx = ((mp >> 1) * 64 + lane) * 8 + 4 * (mp & 1);    // b64 dest in YST

    union PK { f16x8 v8; h16x2 p2[4]; };
    union YS { f16x2v p[2]; h16x4 v; };

    f16x2v k1p[2], k2p[2], k3p[2], k4p[2], k5p[2], k6p[2], k7p[2];
    f16x2v yrp[2], ysp[2];
    float yr[4];

#define STOREYS() do { YS U_; U_.p[0] = ysp[0]; U_.p[1] = ysp[1];            \
    *(h16x4*)(sm + YST + ysIdx) = U_.v; } while (0)

    // ---- init: y = x0 (G3 C layout: d = 16mp+4g+reg, n = row), slot 0, ys ----
    {
        float4 v = *(const float4*)&x0[row * DD + 16 * mp + 4 * g];
        yr[0] = v.x; yr[1] = v.y; yr[2] = v.z; yr[3] = v.w;
        *(float4*)&out[row * (TT * DD) + 16 * mp + 4 * g] = v;
        yrp[0] = pk2(v.x, v.y); yrp[1] = pk2(v.z, v.w);
        ysp[0] = yrp[0]; ysp[1] = yrp[1];
        STOREYS();
    }

    // One MLP eval: YST (ready pre-B1) -> dstp[2] = packed k at (d=16mp+4g+reg, row).
    auto EVAL = [&](f16x2v* dstp) {
        __syncthreads();    // B1: YST ready; H1T free (readers done before prev B3)
        f32x4 c0, c1;
        #pragma unroll
        for (int k = 0; k < 4; ++k) { c0[k] = KF(b1p[0], k); c1[k] = KF(b1p[1], k); }
        #pragma unroll
        for (int kt = 0; kt < 2; ++kt) {
            f16x8 B = *(const f16x8*)(sm + YST + (kt * 64 + lane) * 8);
            c0 = __builtin_amdgcn_mfma_f32_16x16x32_f16(A1r[0][kt], B, c0, 0, 0, 0);
            c1 = __builtin_amdgcn_mfma_f32_16x16x32_f16(A1r[1][kt], B, c1, 0, 0, 0);
        }
        {   // pack h1 = texp(C) -> one lane-contiguous b128 (sigma2: j = 4*mi + reg)
            PK u;
            u.p2[0] = __builtin_amdgcn_cvt_pkrtz(texp(c0[0]), texp(c0[1]));
            u.p2[1] = __builtin_amdgcn_cvt_pkrtz(texp(c0[2]), texp(c0[3]));
            u.p2[2] = __builtin_amdgcn_cvt_pkrtz(texp(c1[0]), texp(c1[1]));
            u.p2[3] = __builtin_amdgcn_cvt_pkrtz(texp(c1[2]), texp(c1[3]));
            *(f16x8*)(sm + H1T + hDst) = u.v8;
        }
        __syncthreads();    // B2: H1T ready; H2T free
        f32x4 d0, d1;
        #pragma unroll
        for (int k = 0; k < 4; ++k) { d0[k] = KF(b2p[0], k); d1[k] = KF(b2p[1], k); }
        #pragma unroll
        for (int kt = 0; kt < 4; ++kt) {
            f16x8 B = *(const f16x8*)(sm + H1T + (kt * 64 + lane) * 8);
            d0 = __builtin_amdgcn_mfma_f32_16x16x32_f16(A2r[0][kt], B, d0, 0, 0, 0);
            d1 = __builtin_amdgcn_mfma_f32_16x16x32_f16(A2r[1][kt], B, d1, 0, 0, 0);
        }
        {   // pack h2 -> b128
            PK u;
            u.p2[0] = __builtin_amdgcn_cvt_pkrtz(texp(d0[0]), texp(d0[1]));
            u.p2[1] = __builtin_amdgcn_cvt_pkrtz(texp(d0[2]), texp(d0[3]));
            u.p2[2] = __builtin_amdgcn_cvt_pkrtz(texp(d1[0]), texp(d1[1]));
            u.p2[3] = __builtin_amdgcn_cvt_pkrtz(texp(d1[2]), texp(d1[3]));
            *(f16x8*)(sm + H2T + hDst) = u.v8;
        }
        __syncthreads();    // B3: H2T ready
        f32x4 e;
        #pragma unroll
        for (int k = 0; k < 4; ++k) e[k] = KF(b3p, k);
        #pragma unroll
        for (int kt = 0; kt < 4; ++kt) {
            f16x8 B = *(const f16x8*)(sm + H2T + (kt * 64 + lane) * 8);
            e = __builtin_amdgcn_mfma_f32_16x16x32_f16(A3r[kt], B, e, 0, 0, 0);
        }
        dstp[0] = pk2(e[0], e[1]);
        dstp[1] = pk2(e[2], e[3]);
    };

    EVAL(k1p);   // k1 = f(x0)

// stage combo in packed f16 (v_pk_fma): ysp = yrp + dt*(sum C_j k_j)
#define COMBOP(C1, C2, C3, C4, C5, C6) do {                                  \
    const f16x2v _c1 = {CC(C1), CC(C1)}, _c2 = {CC(C2), CC(C2)},             \
                 _c3 = {CC(C3), CC(C3)}, _c4 = {CC(C4), CC(C4)},             \
                 _c5 = {CC(C5), CC(C5)}, _c6 = {CC(C6), CC(C6)};             \
    _Pragma("unroll")                                                        \
    for (int p = 0; p < 2; ++p) {                                            \
        f16x2v a = _c1 * k1p[p];                                             \
        if ((C2) != 0.0) a = _c2 * k2p[p] + a;                               \
        if ((C3) != 0.0) a = _c3 * k3p[p] + a;                               \
        if ((C4) != 0.0) a = _c4 * k4p[p] + a;                               \
        if ((C5) != 0.0) a = _c5 * k5p[p] + a;                               \
        if ((C6) != 0.0) a = _c6 * k6p[p] + a;                               \
        ysp[p] = dt2 * a + yrp[p];                                           \
    } } while (0)

    // 10 macro-steps: ms 0..8 cover [2ms, 2ms+2] (dense midpoint at 2ms+1);
    // ms 9 covers [18, 19] (single, no dense, no FSAL eval).
    #pragma unroll 1
    for (int ms = 0; ms < 10; ++ms) {
        const int s0  = 2 * ms;
        const int dbl = (ms < 9);
        const int s1  = dbl ? s0 + 2 : s0 + 1;
        const float t0v = tg[s0];
        const float dtc = tg[s1] - t0v;
        const f16x2v dt2 = {(f16)dtc, (f16)dtc};

        COMBOP(1.0/5.0, 0, 0, 0, 0, 0);
        STOREYS();  EVAL(k2p);
        COMBOP(3.0/40.0, 9.0/40.0, 0, 0, 0, 0);
        STOREYS();  EVAL(k3p);
        COMBOP(44.0/45.0, -56.0/15.0, 32.0/9.0, 0, 0, 0);
        STOREYS();  EVAL(k4p);
        COMBOP(19372.0/6561.0, -25360.0/2187.0, 64448.0/6561.0, -212.0/729.0, 0, 0);
        STOREYS();  EVAL(k5p);
        COMBOP(9017.0/3168.0, -355.0/33.0, 46732.0/5247.0, 49.0/176.0, -5103.0/18656.0, 0);
        STOREYS();  EVAL(k6p);

        // ---- y5 in fp32 (accumulates across macro-steps); keep y0 for dense ----
        float y0s[4], y5[4];
        #pragma unroll
        for (int k = 0; k < 4; ++k) {
            y0s[k] = yr[k];
            float a = (float)(35.0/384.0) * KF(k1p, k);
            a = fmaf((float)(500.0/1113.0),   KF(k3p, k), a);
            a = fmaf((float)(125.0/192.0),    KF(k4p, k), a);
            a = fmaf((float)(-2187.0/6784.0), KF(k5p, k), a);
            a = fmaf((float)(11.0/84.0),      KF(k6p, k), a);
            y5[k] = fmaf(dtc, a, yr[k]);
            yr[k] = y5[k];
        }
        *(float4*)&out[row * (TT * DD) + s1 * DD + 16 * mp + 4 * g] =
            make_float4(y5[0], y5[1], y5[2], y5[3]);
        yrp[0] = pk2(y5[0], y5[1]); yrp[1] = pk2(y5[2], y5[3]);

        if (dbl) {
            // FSAL: k7 = f(y5) (also next step's k1)
            ysp[0] = yrp[0]; ysp[1] = yrp[1];
            STOREYS();
            EVAL(k7p);

            // DOPRI5 dense output at the skipped grid point s0+1 (order-4 interpolant)
            const float th  = (tg[s0 + 1] - t0v) / dtc;   // ~0.5
            const float th1 = 1.0f - th;
            float ym[4];
            #pragma unroll
            for (int k = 0; k < 4; ++k) {
                float k1v = KF(k1p, k), k3v = KF(k3p, k), k4v = KF(k4p, k);
                float k5v = KF(k5p, k), k6v = KF(k6p, k), k7v = KF(k7p, k);
                float dd = y5[k] - y0s[k];
                float r3 = fmaf(dtc, k1v, -dd);            // h*k1 - delta
                float r4 = dd - dtc * k7v - r3;            // delta - h*k7 - r3
                float r5 = (float)(-12715105075.0/11282082432.0) * k1v;
                r5 = fmaf((float)( 87487479700.0/32700410799.0),  k3v, r5);
                r5 = fmaf((float)(-10690763975.0/1880347072.0),   k4v, r5);
                r5 = fmaf((float)( 701980252875.0/199316789632.0),k5v, r5);
                r5 = fmaf((float)(-1453857185.0/822651844.0),     k6v, r5);
                r5 = fmaf((float)( 69997945.0/29380423.0),        k7v, r5);
                r5 *= dtc;
                float c = fmaf(th1, r5, r4);
                c = fmaf(th, c, r3);
                c = fmaf(th1, c, dd);
                ym[k] = fmaf(th, c, y0s[k]);
            }
            *(float4*)&out[row * (TT * DD) + (s0 + 1) * DD + 16 * mp + 4 * g] =
                make_float4(ym[0], ym[1], ym[2], ym[3]);

            k1p[0] = k7p[0]; k1p[1] = k7p[1];              // FSAL handoff
        }
    }
#undef COMBOP
#undef STOREYS
}

extern "C" void kernel_launch(void* const* d_in, const int* in_sizes, int n_in,
                              void* d_out, int out_size, void* d_ws, size_t ws_size,
                              hipStream_t stream) {
    (void)in_sizes; (void)n_in; (void)out_size; (void)ws_size;
    const float* tg = (const float*)d_in[0];
    const float* x0 = (const float*)d_in[1];
    const float* W1 = (const float*)d_in[2];
    const float* b1 = (const float*)d_in[3];
    const float* W2 = (const float*)d_in[4];
    const float* b2 = (const float*)d_in[5];
    const float* W3 = (const float*)d_in[6];
    const float* b3 = (const float*)d_in[7];
    float* out = (float*)d_out;
    f16*   wf  = (f16*)d_ws;   // 64 KB sigma2 frag-major f16 weights (W1,W2 pre-scaled)

    hipLaunchKernelGGL(prep_w, dim3(128), dim3(256), 0, stream, W1, W2, W3, wf);
    hipLaunchKernelGGL(ode_mfma, dim3(1024), dim3(256), 0, stream,
                       tg, wf, b1, b2, b3, x0, out);
}

// Round 13
// 102.633 us; speedup vs baseline: 1.9793x; 1.7721x over previous
//
#include <hip/hip_runtime.h>
#include <math.h>

#define NN 16384
#define DD 64
#define HH 128
#define TT 20

typedef _Float16 f16;
typedef f16 f16x8 __attribute__((ext_vector_type(8)));
typedef f16 f16x2v __attribute__((ext_vector_type(2)));
typedef __fp16 h16x2 __attribute__((ext_vector_type(2)));   // cvt_pkrtz result type
typedef __fp16 h16x4 __attribute__((ext_vector_type(4)));
typedef float f32x4 __attribute__((ext_vector_type(4)));

#define LOG2E2 2.8853900817779268   // 2*log2(e): tanh(x) = 1 - 2/(exp2(LOG2E2*x)+1)

// sigma2 frag bijection (identical for A and B frags of every GEMM -> correct for
// any internal HW k enumeration): element (lane, j) of a frag-tile holds
//   M[k = 32*kt + 16*(j>>2) + 4*(lane>>4) + (j&3)][m/n = 16*t + (lane&15)].
// Wave owning m-tiles {2mp,2mp+1} ends a GEMM with lane (g,r) holding C values
// at exactly j=0..7 of the next GEMM's B-frag at the same lane -> C->B repack is
// one lane-contiguous ds_write_b128, no cross-lane traffic.
// Global wf layout (f16 units): W1/W2 PRE-SCALED by LOG2E2 (tanh fusion).
#define W1F 0        // [mt 8][kt 2][64][8]  A1[m=h1col][k=d]   = W1^T*LOG2E2 (16 KB)
#define W2F 8192     // [mt 8][kt 4][64][8]  A2[m=h2col][k=h1]  = W2^T*LOG2E2 (32 KB)
#define W3F 24576    // [mt 4][kt 4][64][8]  A3[m=d][k=h2col]   = W3^T        (16 KB)
// LDS (activations only, one n-tile per block, 10 KB):
#define YST 0        // [kt 2][64][8]  B1[k=d][n=row]      (2 KB)
#define H1T 1024     // [kt 4][64][8]  B2[k=h1col][n=row]  (4 KB)
#define H2T 3072     // [kt 4][64][8]  B3[k=h2col][n=row]  (4 KB)
#define SMTOT 5120

#define PIN(x) asm volatile("" : "+v"(x))

__device__ __forceinline__ float texp(float c) {   // tanh from pre-scaled preact
    float t = __builtin_amdgcn_exp2f(c);
    return fmaf(-2.0f, __builtin_amdgcn_rcpf(t + 1.0f), 1.0f);
}
__device__ __forceinline__ f16x2v pk2(float a, float b) {
    return __builtin_bit_cast(f16x2v, __builtin_amdgcn_cvt_pkrtz(a, b));
}
#define CC(x) ((f16)(float)(x))
#define KF(KP, K) ((float)((K) & 1 ? (KP)[(K) >> 1].y : (KP)[(K) >> 1].x))

// Weight prep: fp32 [k][m] row-major -> f16 sigma2 frag-major A-tiles (W1,W2 scaled).
__global__ void __launch_bounds__(256) prep_w(
    const float* __restrict__ W1, const float* __restrict__ W2,
    const float* __restrict__ W3, f16* __restrict__ wf)
{
    int t = blockIdx.x * 256 + threadIdx.x;          // 0..32767
    int l = (t >> 3) & 63, j = t & 7, g = l >> 4, r = l & 15;
    int kj = 16 * (j >> 2) + 4 * g + (j & 3);        // sigma2 within-tile k
    float v;
    if (t < 8192)       { int kt = (t >> 9) & 1, mt = t >> 10;
        v = W1[(32*kt + kj) * HH + 16*mt + r] * (float)LOG2E2; }
    else if (t < 24576) { int u = t - 8192;  int kt = (u >> 9) & 3, mt = u >> 11;
        v = W2[(32*kt + kj) * HH + 16*mt + r] * (float)LOG2E2; }
    else                { int u = t - 24576; int kt = (u >> 9) & 3, mt = u >> 11;
        v = W3[(32*kt + kj) * DD + 16*mt + r]; }
    wf[t] = (f16)v;
}

// Block = 4 waves = one n-tile (16 rows); 1024 blocks = 4 blocks/CU, 4 waves/SIMD.
// Macro-stepping: 9 double-interval DOPRI5 steps + 1 single final step (60 evals).
// Midpoints via cubic Hermite (y0, y5, k1, k7 only — register-cheap; err ~1e-5).
__global__ void __launch_bounds__(256, 4) ode_mfma(
    const float* __restrict__ tg, const f16* __restrict__ wf,
    const float* __restrict__ b1, const float* __restrict__ b2,
    const float* __restrict__ b3,
    const float* __restrict__ x0, float* __restrict__ out)
{
    __shared__ __align__(16) f16 sm[SMTOT];

    const int tid  = threadIdx.x;
    const int lane = tid & 63;
    const int mp   = tid >> 6;            // 0..3: m-pair (G1/G2 m-tiles 2mp,2mp+1); G3 m-tile
    const int g    = lane >> 4;           // 0..3
    const int r    = lane & 15;
    const int row  = (blockIdx.x << 4) + r;

    // ---- weight fragments (sigma2-packed) -> registers ----
    f16x8 A1r[2][2], A2r[2][4], A3r[4];
    #pragma unroll
    for (int mi = 0; mi < 2; ++mi)
        #pragma unroll
        for (int kt = 0; kt < 2; ++kt) {
            A1r[mi][kt] = *(const f16x8*)(wf + W1F + (((2*mp+mi)*2 + kt)*64 + lane)*8);
            PIN(A1r[mi][kt]);
        }
    #pragma unroll
    for (int mi = 0; mi < 2; ++mi)
        #pragma unroll
        for (int kt = 0; kt < 4; ++kt) {
            A2r[mi][kt] = *(const f16x8*)(wf + W2F + (((2*mp+mi)*4 + kt)*64 + lane)*8);
            PIN(A2r[mi][kt]);
        }
    #pragma unroll
    for (int kt = 0; kt < 4; ++kt) {
        A3r[kt] = *(const f16x8*)(wf + W3F + ((mp*4 + kt)*64 + lane)*8);
        PIN(A3r[kt]);
    }

    // biases packed f16; b1/b2 pre-scaled
    f16x2v b1p[2][2], b2p[2][2], b3p[2];
    #pragma unroll
    for (int mi = 0; mi < 2; ++mi)
        #pragma unroll
        for (int q = 0; q < 2; ++q) {
            int o = 32*mp + 16*mi + 4*g + 2*q;
            b1p[mi][q] = pk2(b1[o] * (float)LOG2E2, b1[o+1] * (float)LOG2E2);
            b2p[mi][q] = pk2(b2[o] * (float)LOG2E2, b2[o+1] * (float)LOG2E2);
        }
    #pragma unroll
    for (int q = 0; q < 2; ++q)
        b3p[q] = pk2(b3[16*mp + 4*g + 2*q], b3[16*mp + 4*g + 2*q + 1]);

    // lane-contiguous frag slots (f16 units)
    const int hDst  = (mp * 64 + lane) * 8;                          // b128 dest (tile kt=mp)
    const int ysIdx = ((mp >> 1) * 64 + lane) * 8 + 4 * (mp & 1);    // b64 dest in YST

    union PK { f16x8 v8; h16x2 p2[4]; };
    union YS { f16x2v p[2]; h16x4 v; };

    f16x2v k1p[2], k2p[2], k3p[2], k4p[2], k5p[2], k6p[2], k7p[2];
    f16x2v yrp[2], ysp[2];
    float yr[4];

#define STOREYS() do { YS U_; U_.p[0] = ysp[0]; U_.p[1] = ysp[1];            \
    *(h16x4*)(sm + YST + ysIdx) = U_.v; } while (0)

    // ---- init: y = x0 (G3 C layout: d = 16mp+4g+reg, n = row), slot 0, ys ----
    {
        float4 v = *(const float4*)&x0[row * DD + 16 * mp + 4 * g];
        yr[0] = v.x; yr[1] = v.y; yr[2] = v.z; yr[3] = v.w;
        *(float4*)&out[row * (TT * DD) + 16 * mp + 4 * g] = v;
        yrp[0] = pk2(v.x, v.y); yrp[1] = pk2(v.z, v.w);
        ysp[0] = yrp[0]; ysp[1] = yrp[1];
        STOREYS();
    }

    // One MLP eval: YST (ready pre-B1) -> dstp[2] = packed k at (d=16mp+4g+reg, row).
    auto EVAL = [&](f16x2v* dstp) {
        __syncthreads();    // B1: YST ready; H1T free (readers done before prev B3)
        f32x4 c0, c1;
        #pragma unroll
        for (int k = 0; k < 4; ++k) { c0[k] = KF(b1p[0], k); c1[k] = KF(b1p[1], k); }
        #pragma unroll
        for (int kt = 0; kt < 2; ++kt) {
            f16x8 B = *(const f16x8*)(sm + YST + (kt * 64 + lane) * 8);
            c0 = __builtin_amdgcn_mfma_f32_16x16x32_f16(A1r[0][kt], B, c0, 0, 0, 0);
            c1 = __builtin_amdgcn_mfma_f32_16x16x32_f16(A1r[1][kt], B, c1, 0, 0, 0);
        }
        {   // pack h1 = texp(C) -> one lane-contiguous b128 (sigma2: j = 4*mi + reg)
            PK u;
            u.p2[0] = __builtin_amdgcn_cvt_pkrtz(texp(c0[0]), texp(c0[1]));
            u.p2[1] = __builtin_amdgcn_cvt_pkrtz(texp(c0[2]), texp(c0[3]));
            u.p2[2] = __builtin_amdgcn_cvt_pkrtz(texp(c1[0]), texp(c1[1]));
            u.p2[3] = __builtin_amdgcn_cvt_pkrtz(texp(c1[2]), texp(c1[3]));
            *(f16x8*)(sm + H1T + hDst) = u.v8;
        }
        __syncthreads();    // B2: H1T ready; H2T free
        f32x4 d0, d1;
        #pragma unroll
        for (int k = 0; k < 4; ++k) { d0[k] = KF(b2p[0], k); d1[k] = KF(b2p[1], k); }
        #pragma unroll
        for (int kt = 0; kt < 4; ++kt) {
            f16x8 B = *(const f16x8*)(sm + H1T + (kt * 64 + lane) * 8);
            d0 = __builtin_amdgcn_mfma_f32_16x16x32_f16(A2r[0][kt], B, d0, 0, 0, 0);
            d1 = __builtin_amdgcn_mfma_f32_16x16x32_f16(A2r[1][kt], B, d1, 0, 0, 0);
        }
        {   // pack h2 -> b128
            PK u;
            u.p2[0] = __builtin_amdgcn_cvt_pkrtz(texp(d0[0]), texp(d0[1]));
            u.p2[1] = __builtin_amdgcn_cvt_pkrtz(texp(d0[2]), texp(d0[3]));
            u.p2[2] = __builtin_amdgcn_cvt_pkrtz(texp(d1[0]), texp(d1[1]));
            u.p2[3] = __builtin_amdgcn_cvt_pkrtz(texp(d1[2]), texp(d1[3]));
            *(f16x8*)(sm + H2T + hDst) = u.v8;
        }
        __syncthreads();    // B3: H2T ready
        f32x4 e;
        #pragma unroll
        for (int k = 0; k < 4; ++k) e[k] = KF(b3p, k);
        #pragma unroll
        for (int kt = 0; kt < 4; ++kt) {
            f16x8 B = *(const f16x8*)(sm + H2T + (kt * 64 + lane) * 8);
            e = __builtin_amdgcn_mfma_f32_16x16x32_f16(A3r[kt], B, e, 0, 0, 0);
        }
        dstp[0] = pk2(e[0], e[1]);
        dstp[1] = pk2(e[2], e[3]);
    };

    EVAL(k1p);   // k1 = f(x0)

// stage combo in packed f16 (v_pk_fma): ysp = yrp + dt*(sum C_j k_j)
#define COMBOP(C1, C2, C3, C4, C5, C6) do {                                  \
    const f16x2v _c1 = {CC(C1), CC(C1)}, _c2 = {CC(C2), CC(C2)},             \
                 _c3 = {CC(C3), CC(C3)}, _c4 = {CC(C4), CC(C4)},             \
                 _c5 = {CC(C5), CC(C5)}, _c6 = {CC(C6), CC(C6)};             \
    _Pragma("unroll")                                                        \
    for (int p = 0; p < 2; ++p) {                                            \
        f16x2v a = _c1 * k1p[p];                                             \
        if ((C2) != 0.0) a = _c2 * k2p[p] + a;                               \
        if ((C3) != 0.0) a = _c3 * k3p[p] + a;                               \
        if ((C4) != 0.0) a = _c4 * k4p[p] + a;                               \
        if ((C5) != 0.0) a = _c5 * k5p[p] + a;                               \
        if ((C6) != 0.0) a = _c6 * k6p[p] + a;                               \
        ysp[p] = dt2 * a + yrp[p];                                           \
    } } while (0)

    // 10 macro-steps: ms 0..8 cover [2ms, 2ms+2] (Hermite midpoint at 2ms+1);
    // ms 9 covers [18, 19] (single, no dense, no FSAL eval).
    #pragma unroll 1
    for (int ms = 0; ms < 10; ++ms) {
        const int s0  = 2 * ms;
        const int dbl = (ms < 9);
        const int s1  = dbl ? s0 + 2 : s0 + 1;
        const float t0v = tg[s0];
        const float dtc = tg[s1] - t0v;
        const f16x2v dt2 = {(f16)dtc, (f16)dtc};

        COMBOP(1.0/5.0, 0, 0, 0, 0, 0);
        STOREYS();  EVAL(k2p);
        COMBOP(3.0/40.0, 9.0/40.0, 0, 0, 0, 0);
        STOREYS();  EVAL(k3p);
        COMBOP(44.0/45.0, -56.0/15.0, 32.0/9.0, 0, 0, 0);
        STOREYS();  EVAL(k4p);
        COMBOP(19372.0/6561.0, -25360.0/2187.0, 64448.0/6561.0, -212.0/729.0, 0, 0);
        STOREYS();  EVAL(k5p);
        COMBOP(9017.0/3168.0, -355.0/33.0, 46732.0/5247.0, 49.0/176.0, -5103.0/18656.0, 0);
        STOREYS();  EVAL(k6p);

        // ---- y5 in fp32 (accumulates across macro-steps); keep y0 for Hermite ----
        float y0s[4];
        #pragma unroll
        for (int k = 0; k < 4; ++k) {
            y0s[k] = yr[k];
            float a = (float)(35.0/384.0) * KF(k1p, k);
            a = fmaf((float)(500.0/1113.0),   KF(k3p, k), a);
            a = fmaf((float)(125.0/192.0),    KF(k4p, k), a);
            a = fmaf((float)(-2187.0/6784.0), KF(k5p, k), a);
            a = fmaf((float)(11.0/84.0),      KF(k6p, k), a);
            yr[k] = fmaf(dtc, a, yr[k]);       // yr = y5
        }
        *(float4*)&out[row * (TT * DD) + s1 * DD + 16 * mp + 4 * g] =
            make_float4(yr[0], yr[1], yr[2], yr[3]);
        yrp[0] = pk2(yr[0], yr[1]); yrp[1] = pk2(yr[2], yr[3]);

        if (dbl) {
            // FSAL: k7 = f(y5) (also next step's k1). k2..k6 are dead here.
            ysp[0] = yrp[0]; ysp[1] = yrp[1];
            STOREYS();
            EVAL(k7p);

            // Cubic Hermite at the skipped grid point s0+1 (needs y0, y5, k1, k7)
            const float th  = (tg[s0 + 1] - t0v) / dtc;   // ~0.5
            const float th2 = th * th, th3 = th2 * th;
            const float h00 = 2.f*th3 - 3.f*th2 + 1.f;
            const float h01 = 1.f - h00;
            const float h10 = th3 - 2.f*th2 + th;
            const float h11 = th3 - th2;
            float ym[4];
            #pragma unroll
            for (int k = 0; k < 4; ++k) {
                float kk = h10 * KF(k1p, k);
                kk = fmaf(h11, KF(k7p, k), kk);
                float v = h00 * y0s[k];
                v = fmaf(h01, yr[k], v);
                ym[k] = fmaf(dtc, kk, v);
            }
            *(float4*)&out[row * (TT * DD) + (s0 + 1) * DD + 16 * mp + 4 * g] =
                make_float4(ym[0], ym[1], ym[2], ym[3]);

            k1p[0] = k7p[0]; k1p[1] = k7p[1];              // FSAL handoff
        }
    }
#undef COMBOP
#undef STOREYS
}

extern "C" void kernel_launch(void* const* d_in, const int* in_sizes, int n_in,
                              void* d_out, int out_size, void* d_ws, size_t ws_size,
                              hipStream_t stream) {
    (void)in_sizes; (void)n_in; (void)out_size; (void)ws_size;
    const float* tg = (const float*)d_in[0];
    const float* x0 = (const float*)d_in[1];
    const float* W1 = (const float*)d_in[2];
    const float* b1 = (const float*)d_in[3];
    const float* W2 = (const float*)d_in[4];
    const float* b2 = (const float*)d_in[5];
    const float* W3 = (const float*)d_in[6];
    const float* b3 = (const float*)d_in[7];
    float* out = (float*)d_out;
    f16*   wf  = (f16*)d_ws;   // 64 KB sigma2 frag-major f16 weights (W1,W2 pre-scaled)

    hipLaunchKernelGGL(prep_w, dim3(128), dim3(256), 0, stream, W1, W2, W3, wf);
    hipLaunchKernelGGL(ode_mfma, dim3(1024), dim3(256), 0, stream,
                       tg, wf, b1, b2, b3, x0, out);
}